// Round 9
// baseline (598.772 us; speedup 1.0000x reference)
//
#include <hip/hip_runtime.h>
#include <hip/hip_bf16.h>

#define BB 16
#define SS 2048
#define DD 64
#define NIT 16   // 512 k per wave / 32 k per iter

typedef __attribute__((ext_vector_type(8)))  unsigned short ushort8;
typedef __attribute__((ext_vector_type(8)))  __bf16 bf16x8;
typedef __attribute__((ext_vector_type(16))) float f32x16;

static __device__ __forceinline__ unsigned short f2bf(float x) {
    return __builtin_bit_cast(unsigned short, __float2bfloat16(x));
}
static __device__ __forceinline__ unsigned pk2f(float a, float b) {
    return (unsigned)f2bf(a) | ((unsigned)f2bf(b) << 16);
}
union F4 { float4 v; float a[4]; };

// bf16 MFMA attention, 32x32x16 tiles, barrier-free K-loop (r8 skeleton).
// r8 post-mortem: latency-bound at 2 blocks/CU + DRAM-hostile interleaved
// mask streams. This round: q-tile 32 (grid 1024 = 4 blocks/CU, 4 waves/SIMD)
// and CONTIGUOUS 512-k ranges per wave so mask/K/V streams advance
// sequentially. Compute core byte-identical to proven r5/r8:
// S^T = K*Q^T, P via shfl_xor(32) exchange, O^T = V^T*P^T, mask int32 words.
// No max-subtraction: logits bounded; masked -> p = 1.0f exactly.
__global__ __launch_bounds__(256, 4)
void sdpa_mfma_kernel(const float* __restrict__ Q, const float* __restrict__ K,
                      const float* __restrict__ V, const unsigned int* __restrict__ M,
                      float* __restrict__ O) {
    // smem: Qs 4096 | 4 wave-private V^T tiles (64 d-rows, pitch 80) = 20480
    // epilogue reuse: red 24576 at +0, denx at +24576 (512 B)
    __shared__ __align__(16) char smem[25088];
    char* Qs = smem;

    const int t    = threadIdx.x;
    const int lane = t & 63;
    const int l31  = lane & 31;
    const int half = lane >> 5;
    const int kh   = t >> 6;           // wave owns k in [512*kh, 512*kh+512)
    const int b    = blockIdx.y;
    const int q0   = blockIdx.x * 32;
    char* Vw = smem + 4096 + kh * 5120;   // this wave's private V^T tile

    const float* Qg = Q + ((size_t)b * SS + q0) * DD;
    const unsigned int* Mg = M + (size_t)b * SS * SS + (size_t)q0 * SS;

    const int gk  = lane >> 4;          // V staging: k-granule (8 rows)
    const int d0v = (lane & 15) * 4;    // V staging: d columns
    // lane-private global bases; per-iter advance: K/V 32*DD floats, M 32 words
    const float* kp = K + ((size_t)b * SS + 512 * kh + l31) * DD + 8 * half;
    const float* vp = V + ((size_t)b * SS + 512 * kh + 8 * gk) * DD + d0v;
    const unsigned int* mp = Mg + (size_t)l31 * SS + 512 * kh + 4 * half;

    F4 kf[8], vf[8];
    uint4 mfA[4], mfB[4];

    // ---- prologue: issue tile-0 loads before Q staging (latency cover) ----
    #pragma unroll
    for (int dc = 0; dc < 4; dc++) {
        kf[2 * dc].v     = *(const float4*)(kp + 16 * dc);
        kf[2 * dc + 1].v = *(const float4*)(kp + 16 * dc + 4);
    }
    #pragma unroll
    for (int r = 0; r < 8; r++) vf[r].v = *(const float4*)(vp + r * DD);
    #pragma unroll
    for (int g = 0; g < 4; g++) mfA[g] = *(const uint4*)(mp + 8 * g);

    // ---- stage Q (pre-scaled by 1/temperature), swizzled bf16, 32 rows ----
    {
        const int sr = t >> 3, sc = t & 7;
        const float* src = Qg + sr * DD + sc * 8;
        F4 f0, f1; f0.v = *(const float4*)src; f1.v = *(const float4*)(src + 4);
        ushort8 u;
        #pragma unroll
        for (int e = 0; e < 4; e++) {
            u[e]     = f2bf(f0.a[e] * 0.125f);
            u[e + 4] = f2bf(f1.a[e] * 0.125f);
        }
        *(ushort8*)(Qs + sr * 128 + ((sc ^ (sr & 7)) * 16)) = u;
    }
    __syncthreads();   // the only pre-epilogue barrier

    // ---- preload Q fragments (B operand); all 4 waves share the q-tile ----
    const int qrow = l31;
    bf16x8 bq[4];
    #pragma unroll
    for (int dc = 0; dc < 4; dc++)
        bq[dc] = __builtin_bit_cast(bf16x8, *(const ushort8*)(
            Qs + qrow * 128 + (((2 * dc + half) ^ (qrow & 7)) * 16)));

    f32x16 On0, On1;
    #pragma unroll
    for (int i = 0; i < 16; i++) { On0[i] = 0.f; On1[i] = 0.f; }
    float den_acc = 0.f;

#define ITER(MC, MN, KT) do {                                                  \
    const int ktn_ = ((KT) + 1 < NIT) ? (KT) + 1 : NIT - 1;                    \
    /* 1. mask prefetch for next tile (1.5 iters of depth) */                  \
    {                                                                          \
        const unsigned int* mpp_ = mp + ktn_ * 32;                             \
        _Pragma("unroll")                                                      \
        for (int g = 0; g < 4; g++) MN[g] = *(const uint4*)(mpp_ + 8 * g);     \
    }                                                                          \
    /* 2. cvt K regs (tile KT) -> A fragments */                               \
    bf16x8 ak_[4];                                                             \
    _Pragma("unroll")                                                          \
    for (int dc = 0; dc < 4; dc++) {                                           \
        ushort8 u_;                                                            \
        _Pragma("unroll")                                                      \
        for (int e = 0; e < 4; e++) {                                          \
            u_[e]     = f2bf(kf[2 * dc].a[e]);                                 \
            u_[e + 4] = f2bf(kf[2 * dc + 1].a[e]);                             \
        }                                                                      \
        ak_[dc] = __builtin_bit_cast(bf16x8, u_);                              \
    }                                                                          \
    /* 3. issue K loads for next tile (regs free; ~1 iter of depth) */         \
    {                                                                          \
        const float* kpp_ = kp + (size_t)ktn_ * 2048;                          \
        _Pragma("unroll")                                                      \
        for (int dc = 0; dc < 4; dc++) {                                       \
            kf[2 * dc].v     = *(const float4*)(kpp_ + 16 * dc);               \
            kf[2 * dc + 1].v = *(const float4*)(kpp_ + 16 * dc + 4);           \
        }                                                                      \
    }                                                                          \
    /* 4. QK^T: S^T tile [32k x 32q] */                                        \
    f32x16 S_;                                                                 \
    _Pragma("unroll")                                                          \
    for (int i = 0; i < 16; i++) S_[i] = 0.f;                                  \
    _Pragma("unroll")                                                          \
    for (int dc = 0; dc < 4; dc++)                                             \
        S_ = __builtin_amdgcn_mfma_f32_32x32x16_bf16(ak_[dc], bq[dc], S_, 0, 0, 0); \
    /* 5. mask + exp + den (C row = e + 8g + 4half) */                         \
    float p_[16];                                                              \
    _Pragma("unroll")                                                          \
    for (int g = 0; g < 4; g++) {                                              \
        const unsigned mw_[4] = {MC[g].x, MC[g].y, MC[g].z, MC[g].w};          \
        _Pragma("unroll")                                                      \
        for (int e = 0; e < 4; e++) {                                          \
            const float ev_ = __expf(S_[4 * g + e]);                           \
            const float pv_ = mw_[e] ? 1.0f : ev_;                             \
            p_[4 * g + e] = pv_;                                               \
            den_acc += pv_;                                                    \
        }                                                                      \
    }                                                                          \
    /* 6. V regs (tile KT) -> wave-private LDS (V^T, pitch 80, swizzled) */    \
    _Pragma("unroll")                                                          \
    for (int e = 0; e < 4; e++) {                                              \
        const int d_ = d0v + e;                                                \
        uint4 pkv_;                                                            \
        pkv_.x = pk2f(vf[0].a[e], vf[1].a[e]);                                 \
        pkv_.y = pk2f(vf[2].a[e], vf[3].a[e]);                                 \
        pkv_.z = pk2f(vf[4].a[e], vf[5].a[e]);                                 \
        pkv_.w = pk2f(vf[6].a[e], vf[7].a[e]);                                 \
        *(uint4*)(Vw + d_ * 80 + (((gk ^ (d_ >> 2)) & 3) * 16)) = pkv_;        \
    }                                                                          \
    /* 7. issue V loads for next tile */                                       \
    {                                                                          \
        const float* vpp_ = vp + (size_t)ktn_ * 2048;                          \
        _Pragma("unroll")                                                      \
        for (int r = 0; r < 8; r++) vf[r].v = *(const float4*)(vpp_ + r * DD); \
    }                                                                          \
    /* 8. P exchange via shfl_xor(32) (proven r5) + PV */                      \
    _Pragma("unroll")                                                          \
    for (int s2 = 0; s2 < 2; s2++) {                                           \
        const unsigned o0 = pk2f(p_[8 * s2 + 0], p_[8 * s2 + 1]);              \
        const unsigned o1 = pk2f(p_[8 * s2 + 2], p_[8 * s2 + 3]);              \
        const unsigned o2 = pk2f(p_[8 * s2 + 4], p_[8 * s2 + 5]);              \
        const unsigned o3 = pk2f(p_[8 * s2 + 6], p_[8 * s2 + 7]);              \
        const unsigned s0 = half ? o0 : o2;                                    \
        const unsigned s1 = half ? o1 : o3;                                    \
        const unsigned r0 = (unsigned)__shfl_xor((int)s0, 32, 64);             \
        const unsigned r1 = (unsigned)__shfl_xor((int)s1, 32, 64);             \
        uint4 bu;                                                              \
        bu.x = half ? r0 : o0;                                                 \
        bu.y = half ? r1 : o1;                                                 \
        bu.z = half ? o2 : r0;                                                 \
        bu.w = half ? o3 : r1;                                                 \
        const bf16x8 bp = __builtin_bit_cast(bf16x8, bu);                      \
        _Pragma("unroll")                                                      \
        for (int dc2 = 0; dc2 < 2; dc2++) {                                    \
            const int vrow = 32 * dc2 + l31;                                   \
            bf16x8 av = __builtin_bit_cast(bf16x8, *(const ushort8*)(          \
                Vw + vrow * 80 + ((((2 * s2 + half) ^ (vrow >> 2)) & 3) * 16))); \
            if (dc2 == 0) On0 = __builtin_amdgcn_mfma_f32_32x32x16_bf16(av, bp, On0, 0, 0, 0); \
            else          On1 = __builtin_amdgcn_mfma_f32_32x32x16_bf16(av, bp, On1, 0, 0, 0); \
        }                                                                      \
    }                                                                          \
} while (0)

    for (int kt = 0; kt < NIT; kt += 2) {
        ITER(mfA, mfB, kt);
        ITER(mfB, mfA, kt + 1);
    }
#undef ITER

    // ---- epilogue: lane halves, then 4-way k-range reduction via LDS ----
    const float den_tot = den_acc + __shfl_xor(den_acc, 32, 64);
    float* red  = (float*)smem;             // 24 KB scratch (loop LDS dead)
    float* denx = (float*)(smem + 24576);

    __syncthreads();
    if (kh != 0) {
        #pragma unroll
        for (int dc = 0; dc < 2; dc++)
            #pragma unroll
            for (int g = 0; g < 4; g++) {
                const f32x16& Oc = dc ? On1 : On0;
                float4 st;
                st.x = Oc[4 * g + 0]; st.y = Oc[4 * g + 1];
                st.z = Oc[4 * g + 2]; st.w = Oc[4 * g + 3];
                *(float4*)((char*)red + (kh - 1) * 8192 + (dc * 4 + g) * 1024 + lane * 16) = st;
            }
        if (lane < 32) denx[kh * 32 + l31] = den_tot;
    }
    __syncthreads();
    if (kh == 0) {
        const float inv = 1.0f / (den_tot + denx[32 + l31] + denx[64 + l31] + denx[96 + l31]);
        float* Og = O + ((size_t)b * SS + q0 + qrow) * DD;
        #pragma unroll
        for (int dc = 0; dc < 2; dc++)
            #pragma unroll
            for (int g = 0; g < 4; g++) {
                const f32x16& Oc = dc ? On1 : On0;
                float4 st;
                st.x = Oc[4 * g + 0]; st.y = Oc[4 * g + 1];
                st.z = Oc[4 * g + 2]; st.w = Oc[4 * g + 3];
                #pragma unroll
                for (int w2 = 0; w2 < 3; w2++) {
                    const float4 pr = *(const float4*)((char*)red + w2 * 8192 +
                                                       (dc * 4 + g) * 1024 + lane * 16);
                    st.x += pr.x; st.y += pr.y; st.z += pr.z; st.w += pr.w;
                }
                st.x *= inv; st.y *= inv; st.z *= inv; st.w *= inv;
                // d = e + 8g + 4half + 32dc  (C-row formula)
                *(float4*)(Og + 32 * dc + 8 * g + 4 * half) = st;
            }
    }
}

extern "C" void kernel_launch(void* const* d_in, const int* in_sizes, int n_in,
                              void* d_out, int out_size, void* d_ws, size_t ws_size,
                              hipStream_t stream) {
    const float* q = (const float*)d_in[0];
    const float* k = (const float*)d_in[1];
    const float* v = (const float*)d_in[2];
    const unsigned int* m = (const unsigned int*)d_in[3];
    float* out = (float*)d_out;

    dim3 grid(SS / 32, BB);   // 64 x 16 = 1024 blocks -> 4 per CU
    sdpa_mfma_kernel<<<grid, 256, 0, stream>>>(q, k, v, m, out);
}

// Round 10
// 439.477 us; speedup vs baseline: 1.3625x; 1.3625x over previous
//
#include <hip/hip_runtime.h>
#include <hip/hip_bf16.h>

#define BB 16
#define SS 2048
#define DD 64
#define NT (SS / 64)

typedef __attribute__((ext_vector_type(8)))  unsigned short ushort8;
typedef __attribute__((ext_vector_type(8)))  __bf16 bf16x8;
typedef __attribute__((ext_vector_type(16))) float f32x16;

static __device__ __forceinline__ unsigned short f2bf(float x) {
    return __builtin_bit_cast(unsigned short, __float2bfloat16(x));
}
static __device__ __forceinline__ unsigned pk2(float a, float b) {
    return (unsigned)f2bf(a) | ((unsigned)f2bf(b) << 16);
}
union F4 { float4 v; float a[4]; };

// bf16 MFMA attention, 32x32x16 tiles (q64/k64 proven r5 core).
// r9 post-mortem: all prior rounds were DRAM-efficiency-bound on the mask
// (32+ interleaved 8KB-strided row streams per block -> page thrash, <30%
// HBM eff). Fix: Phase A bitpacks each block's CONTIGUOUS 512 KB mask region
// (sequential row-major, fill-kernel access shape, ~80% eff) into a 16 KB
// LDS bit-tile; Phase B is the r5 loop with mask = 1 ds_read_b32 + bit test.
// Mask = int32 words (proven r4-r9). No max-subtraction: logits bounded;
// masked -> p = 1.0f exactly (exp(1e-9)==1.0f).
__global__ __launch_bounds__(256, 2)
void sdpa_mfma_kernel(const float* __restrict__ Q, const float* __restrict__ K,
                      const float* __restrict__ V, const unsigned int* __restrict__ M,
                      float* __restrict__ O) {
    // smem: Qs 8K | Ks 8K | Vs 8K | Bits 16K ([kw 0..63][q' 0..63] dwords,
    // q' = (q + kw) & 63 bank rotation). Epilogue reuse: red = +8192 (16K),
    // denx = +24576 (r5 offsets, regions dead after loop).
    __shared__ __align__(16) char smem[40960];
    char* Qs   = smem;
    char* Ks   = smem + 8192;
    char* Vs   = smem + 16384;
    char* Bits = smem + 24576;

    const int t    = threadIdx.x;
    const int lane = t & 63;
    const int l31  = lane & 31;
    const int half = lane >> 5;
    const int w    = t >> 6;
    const int qs   = w & 1;    // q-subtile
    const int kh   = w >> 1;   // k-split half
    const int b    = blockIdx.y;
    const int q0   = blockIdx.x * 64;

    const float* Qg = Q + ((size_t)b * SS + q0) * DD;
    const float* Kg = K + (size_t)b * SS * DD;
    const float* Vg = V + (size_t)b * SS * DD;

    const int sr = t >> 2;     // staging row 0..63
    const int sc = t & 3;      // staging col group 0..3 (16 elems each)

    // ---- stage Q tile (pre-scaled by 1/temperature), swizzled bf16 ----
    {
        F4 f0, f1, f2, f3;
        const float* src = Qg + sr * DD + sc * 16;
        f0.v = *(const float4*)(src);
        f1.v = *(const float4*)(src + 4);
        f2.v = *(const float4*)(src + 8);
        f3.v = *(const float4*)(src + 12);
        ushort8 u0, u1;
        #pragma unroll
        for (int e = 0; e < 4; e++) {
            u0[e]     = f2bf(f0.a[e] * 0.125f);
            u0[e + 4] = f2bf(f1.a[e] * 0.125f);
            u1[e]     = f2bf(f2.a[e] * 0.125f);
            u1[e + 4] = f2bf(f3.a[e] * 0.125f);
        }
        *(ushort8*)(Qs + sr * 128 + (((sc * 2)     ^ (sr & 7)) * 16)) = u0;
        *(ushort8*)(Qs + sr * 128 + (((sc * 2 + 1) ^ (sr & 7)) * 16)) = u1;
    }
    __syncthreads();

    // ---- preload Q fragments (B operand), kept in registers all loop ----
    const int qrow = 32 * qs + l31;
    ushort8 bq[4];
    #pragma unroll
    for (int dc = 0; dc < 4; dc++)
        bq[dc] = *(const ushort8*)(Qs + qrow * 128 + (((2 * dc + half) ^ (qrow & 7)) * 16));

    // ---- Phase A: bitpack this block's mask region (64 rows x 8 KB,
    // 512 KB contiguous, sequential DRAM order) into Bits ----
    {
        const unsigned int* Mblk = M + (size_t)b * SS * SS + (size_t)q0 * SS;
        const int kw  = t >> 2;
        const int bsh = 8 * (t & 3);
        for (int s = 0; s < 64; ++s) {
            const unsigned int* rp = Mblk + (size_t)s * SS + 8 * t;
            const uint4 a0 = *(const uint4*)(rp);
            const uint4 a1 = *(const uint4*)(rp + 4);
            unsigned byt = (unsigned)(a0.x != 0u)        | ((unsigned)(a0.y != 0u) << 1)
                         | ((unsigned)(a0.z != 0u) << 2) | ((unsigned)(a0.w != 0u) << 3)
                         | ((unsigned)(a1.x != 0u) << 4) | ((unsigned)(a1.y != 0u) << 5)
                         | ((unsigned)(a1.z != 0u) << 6) | ((unsigned)(a1.w != 0u) << 7);
            unsigned v = byt << bsh;
            v |= (unsigned)__shfl_xor((int)v, 1, 64);
            v |= (unsigned)__shfl_xor((int)v, 2, 64);
            if ((t & 3) == 0)
                *(unsigned*)(Bits + kw * 256 + (((s + kw) & 63) << 2)) = v;
        }
    }
    __syncthreads();

    f32x16 On0, On1;           // O^T accumulators: d 0..31 / 32..63
    #pragma unroll
    for (int i = 0; i < 16; i++) { On0[i] = 0.f; On1[i] = 0.f; }
    float den_acc = 0.f;

    const int krow = 32 * kh + l31;
    const int d0v  = (t & 15) * 4;   // V staging: d columns
    const int kk4  = (t >> 4) * 4;   // V staging: k row quad base

    // ---- Phase B: r5-proven loop, mask from LDS bits ----
    for (int kt = 0; kt < NT; ++kt) {
        __syncthreads();   // previous PV done reading Ks/Vs

        // ---- stage K tile (swizzled bf16, r5-proven) ----
        {
            F4 f0, f1, f2, f3;
            const float* src = Kg + (size_t)(kt * 64 + sr) * DD + sc * 16;
            f0.v = *(const float4*)(src);
            f1.v = *(const float4*)(src + 4);
            f2.v = *(const float4*)(src + 8);
            f3.v = *(const float4*)(src + 12);
            ushort8 u0, u1;
            #pragma unroll
            for (int e = 0; e < 4; e++) {
                u0[e]     = f2bf(f0.a[e]);
                u0[e + 4] = f2bf(f1.a[e]);
                u1[e]     = f2bf(f2.a[e]);
                u1[e + 4] = f2bf(f3.a[e]);
            }
            *(ushort8*)(Ks + sr * 128 + (((sc * 2)     ^ (sr & 7)) * 16)) = u0;
            *(ushort8*)(Ks + sr * 128 + (((sc * 2 + 1) ^ (sr & 7)) * 16)) = u1;
        }
        // ---- stage V transposed: Vs[d][k], uint2 writes (r8-proven form) ----
        {
            const float* src = Vg + (size_t)(kt * 64 + kk4) * DD + d0v;
            F4 r0, r1, r2, r3;
            r0.v = *(const float4*)(src);
            r1.v = *(const float4*)(src + DD);
            r2.v = *(const float4*)(src + 2 * DD);
            r3.v = *(const float4*)(src + 3 * DD);
            #pragma unroll
            for (int e = 0; e < 4; e++) {
                const int d = d0v + e;
                *(uint2*)(Vs + d * 128 + (((kk4 >> 3) ^ (d & 7)) * 16) + (kk4 & 7) * 2)
                    = make_uint2(pk2(r0.a[e], r1.a[e]), pk2(r2.a[e], r3.a[e]));
            }
        }
        __syncthreads();

        // ---- QK^T: S^T tile [32k x 32q] ----
        f32x16 S;
        #pragma unroll
        for (int i = 0; i < 16; i++) S[i] = 0.f;
        #pragma unroll
        for (int dc = 0; dc < 4; dc++) {
            bf16x8 ak = __builtin_bit_cast(bf16x8,
                *(const ushort8*)(Ks + krow * 128 + (((2 * dc + half) ^ (krow & 7)) * 16)));
            S = __builtin_amdgcn_mfma_f32_32x32x16_bf16(
                    ak, __builtin_bit_cast(bf16x8, bq[dc]), S, 0, 0, 0);
        }

        // ---- mask bits + exp + denominator (C row = e + 8g + 4half) ----
        const unsigned bitw = *(const unsigned*)(Bits + (2 * kt + kh) * 256 +
                                  (((qrow + 2 * kt + kh) & 63) << 2));
        float p[16];
        #pragma unroll
        for (int g = 0; g < 4; g++) {
            #pragma unroll
            for (int e = 0; e < 4; e++) {
                const float ev = __expf(S[4 * g + e]);
                const float pv = ((bitw >> (4 * half + 8 * g + e)) & 1u) ? 1.0f : ev;
                p[4 * g + e] = pv;
                den_acc += pv;
            }
        }

        // ---- P·V: B-operand frags via shfl_xor(32) (proven r5), 2 ksubs ----
        #pragma unroll
        for (int s2 = 0; s2 < 2; s2++) {
            const unsigned o0 = pk2(p[8 * s2 + 0], p[8 * s2 + 1]);
            const unsigned o1 = pk2(p[8 * s2 + 2], p[8 * s2 + 3]);
            const unsigned o2 = pk2(p[8 * s2 + 4], p[8 * s2 + 5]);
            const unsigned o3 = pk2(p[8 * s2 + 6], p[8 * s2 + 7]);
            const unsigned s0 = half ? o0 : o2;
            const unsigned s1 = half ? o1 : o3;
            const unsigned r0 = (unsigned)__shfl_xor((int)s0, 32, 64);
            const unsigned r1 = (unsigned)__shfl_xor((int)s1, 32, 64);
            uint4 bu;
            bu.x = half ? r0 : o0;
            bu.y = half ? r1 : o1;
            bu.z = half ? o2 : r0;
            bu.w = half ? o3 : r1;
            const bf16x8 bp = __builtin_bit_cast(bf16x8, bu);
            #pragma unroll
            for (int dc = 0; dc < 2; dc++) {
                const int vrow = 32 * dc + l31;
                bf16x8 av = __builtin_bit_cast(bf16x8,
                    *(const ushort8*)(Vs + vrow * 128 +
                        (((4 * kh + 2 * s2 + half) ^ (vrow & 7)) * 16)));
                if (dc == 0) On0 = __builtin_amdgcn_mfma_f32_32x32x16_bf16(av, bp, On0, 0, 0, 0);
                else         On1 = __builtin_amdgcn_mfma_f32_32x32x16_bf16(av, bp, On1, 0, 0, 0);
            }
        }
    }

    // ---- epilogue: combine lane halves, then the two k-split waves ----
    const float den_tot = den_acc + __shfl_xor(den_acc, 32, 64);
    float* red  = (float*)(smem + 8192);    // Ks+Vs (dead)
    float* denx = (float*)(smem + 24576);   // Bits (dead)

    __syncthreads();
    if (kh == 1) {
        #pragma unroll
        for (int dc = 0; dc < 2; dc++)
            #pragma unroll
            for (int g = 0; g < 4; g++) {
                const f32x16& Oc = dc ? On1 : On0;
                float4 st;
                st.x = Oc[4 * g + 0]; st.y = Oc[4 * g + 1];
                st.z = Oc[4 * g + 2]; st.w = Oc[4 * g + 3];
                *(float4*)((char*)red + qs * 8192 + (dc * 4 + g) * 1024 + lane * 16) = st;
            }
        if (lane < 32) denx[qs * 32 + l31] = den_tot;
    }
    __syncthreads();
    if (kh == 0) {
        const float inv = 1.0f / (den_tot + denx[qs * 32 + l31]);
        float* Og = O + ((size_t)b * SS + q0 + qrow) * DD;
        #pragma unroll
        for (int dc = 0; dc < 2; dc++)
            #pragma unroll
            for (int g = 0; g < 4; g++) {
                const float4 pr = *(const float4*)((char*)red + qs * 8192 + (dc * 4 + g) * 1024 + lane * 16);
                const f32x16& Oc = dc ? On1 : On0;
                float4 st;
                st.x = (Oc[4 * g + 0] + pr.x) * inv;
                st.y = (Oc[4 * g + 1] + pr.y) * inv;
                st.z = (Oc[4 * g + 2] + pr.z) * inv;
                st.w = (Oc[4 * g + 3] + pr.w) * inv;
                // d = e + 8g + 4half + 32dc  (C-row formula)
                *(float4*)(Og + 32 * dc + 8 * g + 4 * half) = st;
            }
    }
}

extern "C" void kernel_launch(void* const* d_in, const int* in_sizes, int n_in,
                              void* d_out, int out_size, void* d_ws, size_t ws_size,
                              hipStream_t stream) {
    const float* q = (const float*)d_in[0];
    const float* k = (const float*)d_in[1];
    const float* v = (const float*)d_in[2];
    const unsigned int* m = (const unsigned int*)d_in[3];
    float* out = (float*)d_out;

    dim3 grid(SS / 64, BB);   // 32 x 16 = 512 blocks -> 2 per CU
    sdpa_mfma_kernel<<<grid, 256, 0, stream>>>(q, k, v, m, out);
}